// Round 12
// baseline (87.898 us; speedup 1.0000x reference)
//
#include <hip/hip_runtime.h>
#include <cstdint>

typedef short bf16x8 __attribute__((ext_vector_type(8)));
typedef float f32x4 __attribute__((ext_vector_type(4)));
typedef uint16_t u16x4 __attribute__((ext_vector_type(4)));

#define MFMA_16x16x32(a, b, c) __builtin_amdgcn_mfma_f32_16x16x32_bf16((a), (b), (c), 0, 0, 0)

static constexpr int BATCH = 2;
static constexpr int HEADS = 12;
static constexpr int BH    = BATCH * HEADS;   // 24
static constexpr int NCTX  = 2048;
static constexpr int DH    = 64;
static constexpr int EMB   = 768;

// 0.125 * log2(e): Q pre-scale so softmax runs in exp2 domain
static constexpr float QSCALE = 0.125f * 1.44269504088896340736f;

// ---------- bf16 helpers (raw-bit, RN rounding) ----------
__device__ __forceinline__ uint16_t f2bf(float x) {
    uint32_t u = __float_as_uint(x);
    u += 0x7FFFu + ((u >> 16) & 1u);
    return (uint16_t)(u >> 16);
}
__device__ __forceinline__ uint32_t cvt_pk_bf16(float lo, float hi) {
    uint32_t r;
    asm("v_cvt_pk_bf16_f32 %0, %1, %2" : "=v"(r) : "v"(lo), "v"(hi));
    return r;
}

// ---------- merged convert: K (range [0,n4a)) and W (range [n4a,n4a+n4b)) ----------
__global__ void k_cvt2(const float* __restrict__ a, uint16_t* __restrict__ da, int n4a,
                       const float* __restrict__ b2, uint16_t* __restrict__ db, int n4b) {
    int i = blockIdx.x * blockDim.x + threadIdx.x;
    const float* src; uint16_t* dst; int j;
    if (i < n4a) { src = a; dst = da; j = i; }
    else {
        j = i - n4a;
        if (j >= n4b) return;
        src = b2; dst = db;
    }
    float4 v = reinterpret_cast<const float4*>(src)[j];
    u16x4 hv = {f2bf(v.x), f2bf(v.y), f2bf(v.z), f2bf(v.w)};
    reinterpret_cast<u16x4*>(dst)[j] = hv;
}

// ---------- V transpose+convert to PV-fragment layout (R10, unchanged) ----------
// vf[((bh*32 + t)*8 + slot)*512 + l*8 + j] = V[kv=64t+32h+8g+j][d=16f+c]
// where slot=2f+h, l=16g+c. Each k_attn B-fragment load is one fully
// coalesced 1KB instruction.
__global__ __launch_bounds__(256) void k_vt(const float* __restrict__ v,
                                            uint16_t* __restrict__ vt) {
    const int bh = blockIdx.y;
    const int n0 = blockIdx.x * 64;
    const int t  = threadIdx.x;
    __shared__ uint16_t tileT[64][72];   // [d][n_local]

    const int r  = t >> 2;          // n-row within tile (0..63)
    const int cc = (t & 3) * 16;    // d-col base
    const float* vp = v + ((size_t)bh * NCTX + n0 + r) * DH + cc;
#pragma unroll
    for (int u = 0; u < 4; ++u) {
        float4 x = reinterpret_cast<const float4*>(vp)[u];
        tileT[cc + 4 * u + 0][r] = f2bf(x.x);
        tileT[cc + 4 * u + 1][r] = f2bf(x.y);
        tileT[cc + 4 * u + 2][r] = f2bf(x.z);
        tileT[cc + 4 * u + 3][r] = f2bf(x.w);
    }
    __syncthreads();

    const int l2 = t & 63;          // fragment lane
    const int s0 = t >> 6;          // 0..3
    const int gg = l2 >> 4;
    const int c2 = l2 & 15;
    uint16_t* vb = vt + ((size_t)bh * 32 + (n0 >> 6)) * 8 * 512;
#pragma unroll
    for (int u = 0; u < 2; ++u) {
        const int slot = s0 + 4 * u;        // 0..7
        const int f = slot >> 1, h = slot & 1;
        bf16x8 x = *reinterpret_cast<const bf16x8*>(&tileT[f * 16 + c2][h * 32 + 8 * gg]);
        *reinterpret_cast<bf16x8*>(vb + (size_t)slot * 512 + l2 * 8) = x;
    }
}

// ---------- flash attention ----------
// R10 structure with KV tiles processed in PAIRS (128 kv per loop iteration):
// one staging phase + one defer-max ballot + halved loop overhead per 128 kv.
// grid (NCTX/64, BH), 4 waves, wave owns 16 q-rows. V in registers (R10).
__global__ __launch_bounds__(256) void k_attn(
        const float* __restrict__ q, const uint16_t* __restrict__ kb,
        const uint16_t* __restrict__ vf, uint16_t* __restrict__ xb) {
    const int bh = blockIdx.y;
    const int b  = bh / HEADS;
    const int h  = bh % HEADS;
    const int tid = threadIdx.x;
    const int w = tid >> 6;
    const int l = tid & 63;
    const int g = l >> 4;    // 16-lane group 0..3
    const int c = l & 15;

    __shared__ uint16_t K_s[128][72];     // one KV PAIR (128 rows)
    __shared__ uint16_t P_s[4][16][72];   // [wave][q][kv-half]

    const int q0 = blockIdx.x * 64 + w * 16;
    constexpr int NP = NCTX / 128;        // 16 pairs

    // Q fragments: load fp32 direct, scale by 0.125*log2e, convert in-reg
    bf16x8 qa[2];
    {
        const float* qp = q + ((size_t)bh * NCTX + q0 + c) * DH + 8 * g;
#pragma unroll
        for (int kf = 0; kf < 2; ++kf) {
            float4 x0 = *reinterpret_cast<const float4*>(qp + kf * 32);
            float4 x1 = *reinterpret_cast<const float4*>(qp + kf * 32 + 4);
            bf16x8 f;
            f[0] = (short)f2bf(x0.x * QSCALE); f[1] = (short)f2bf(x0.y * QSCALE);
            f[2] = (short)f2bf(x0.z * QSCALE); f[3] = (short)f2bf(x0.w * QSCALE);
            f[4] = (short)f2bf(x1.x * QSCALE); f[5] = (short)f2bf(x1.y * QSCALE);
            f[6] = (short)f2bf(x1.z * QSCALE); f[7] = (short)f2bf(x1.w * QSCALE);
            qa[kf] = f;
        }
    }

    f32x4 zero = {0.f, 0.f, 0.f, 0.f};
    f32x4 o[4] = {zero, zero, zero, zero};
    float m = -1e30f;     // running max (log2 units), per q=c (uniform across groups)
    float lsum = 0.f;     // lane-partial softmax denominator for q=c

    // K staging: 256 thr -> 32 rows x 8 chunks, FOUR row-passes (128 rows)
    const int srow = tid >> 3;      // 0..31
    const int sch  = tid & 7;       // 0..7

    const uint16_t* kb_b = kb + ((size_t)bh * NCTX + srow) * DH + sch * 8;
    const uint16_t* vf_b = vf + (size_t)bh * 32 * 8 * 512 + (size_t)l * 8;

    // prologue: stage pair 0 (kv rows 0..127)
#pragma unroll
    for (int u = 0; u < 4; ++u) {
        bf16x8 a0 = *reinterpret_cast<const bf16x8*>(kb_b + (size_t)u * 32 * DH);
        *reinterpret_cast<bf16x8*>(&K_s[srow + 32 * u][sch * 8]) = a0;
    }
    __syncthreads();

    for (int tp = 0; tp < NP; ++tp) {
        // prefetch next pair's K into regs (consumed after the barrier below)
        bf16x8 nk[4];
        const bool pf = (tp + 1) < NP;
        if (pf) {
            const size_t ko = (size_t)(tp + 1) * 128 * DH;
#pragma unroll
            for (int u = 0; u < 4; ++u)
                nk[u] = *reinterpret_cast<const bf16x8*>(kb_b + ko + (size_t)u * 32 * DH);
        }

        // V fragments for half A (tile 2tp), issued ~full half ahead of PV-A
        bf16x8 vra[8];
#pragma unroll
        for (int s2 = 0; s2 < 8; ++s2)
            vra[s2] = *reinterpret_cast<const bf16x8*>(vf_b + ((size_t)(2 * tp) * 8 + s2) * 512);

        // ---- S^T over the full pair: s[nf8][r] = S[kv=16nf8+4g+r][q=c], nf8=0..7
        f32x4 s[8];
#pragma unroll
        for (int nf = 0; nf < 8; ++nf) s[nf] = zero;
        __builtin_amdgcn_s_setprio(1);
#pragma unroll
        for (int nf = 0; nf < 8; ++nf) {
#pragma unroll
            for (int kf = 0; kf < 2; ++kf) {
                bf16x8 bhf = *reinterpret_cast<const bf16x8*>(&K_s[nf * 16 + c][kf * 32 + 8 * g]);
                s[nf] = MFMA_16x16x32(bhf, qa[kf], s[nf]);
            }
        }
        __builtin_amdgcn_s_setprio(0);

        // V fragments for half B (tile 2tp+1), cover = softmax-A + PV-A
        bf16x8 vrb[8];
#pragma unroll
        for (int s2 = 0; s2 < 8; ++s2)
            vrb[s2] = *reinterpret_cast<const bf16x8*>(vf_b + ((size_t)(2 * tp + 1) * 8 + s2) * 512);

        // ---- fused per-lane partial max over all 32 kv slots (tree)
        float pmax;
        {
            float t0 = fmaxf(fmaxf(s[0][0], s[0][1]), fmaxf(s[0][2], s[0][3]));
            float t1 = fmaxf(fmaxf(s[1][0], s[1][1]), fmaxf(s[1][2], s[1][3]));
            float t2 = fmaxf(fmaxf(s[2][0], s[2][1]), fmaxf(s[2][2], s[2][3]));
            float t3 = fmaxf(fmaxf(s[3][0], s[3][1]), fmaxf(s[3][2], s[3][3]));
            float t4 = fmaxf(fmaxf(s[4][0], s[4][1]), fmaxf(s[4][2], s[4][3]));
            float t5 = fmaxf(fmaxf(s[5][0], s[5][1]), fmaxf(s[5][2], s[5][3]));
            float t6 = fmaxf(fmaxf(s[6][0], s[6][1]), fmaxf(s[6][2], s[6][3]));
            float t7 = fmaxf(fmaxf(s[7][0], s[7][1]), fmaxf(s[7][2], s[7][3]));
            pmax = fmaxf(fmaxf(fmaxf(t0, t1), fmaxf(t2, t3)),
                         fmaxf(fmaxf(t4, t5), fmaxf(t6, t7)));
        }

        // deferred max, ONE ballot per 128 kv (equivalence per R9 argument)
        if (!__all(pmax <= m + 11.0f)) {
            float smax = fmaxf(pmax, __shfl_xor(pmax, 16));
            smax = fmaxf(smax, __shfl_xor(smax, 32));
            float mnew = fmaxf(m, smax);
            float corr = __builtin_amdgcn_exp2f(m - mnew);
            m = mnew;
            lsum *= corr;
#pragma unroll
            for (int r = 0; r < 4; ++r) {
                float cr = __shfl(corr, 4 * g + r);   // corr for q-local 4g+r
#pragma unroll
                for (int f = 0; f < 4; ++f) o[f][r] *= cr;
            }
        }

        // ---- half A: p = exp2(s-m), pack, P_s round-trip, PV with vra
#pragma unroll
        for (int nf = 0; nf < 4; ++nf) {
            float p0 = __builtin_amdgcn_exp2f(s[nf][0] - m);
            float p1 = __builtin_amdgcn_exp2f(s[nf][1] - m);
            float p2 = __builtin_amdgcn_exp2f(s[nf][2] - m);
            float p3 = __builtin_amdgcn_exp2f(s[nf][3] - m);
            lsum += (p0 + p1) + (p2 + p3);
            uint2 pk;
            pk.x = cvt_pk_bf16(p0, p1);
            pk.y = cvt_pk_bf16(p2, p3);
            *reinterpret_cast<uint2*>(&P_s[w][c][16 * nf + 4 * g]) = pk;
        }
        {
            bf16x8 pa0 = *reinterpret_cast<const bf16x8*>(&P_s[w][c][8 * g]);
            bf16x8 pa1 = *reinterpret_cast<const bf16x8*>(&P_s[w][c][32 + 8 * g]);
            __builtin_amdgcn_s_setprio(1);
#pragma unroll
            for (int f = 0; f < 4; ++f) {
                o[f] = MFMA_16x16x32(pa0, vra[2 * f],     o[f]);
                o[f] = MFMA_16x16x32(pa1, vra[2 * f + 1], o[f]);
            }
            __builtin_amdgcn_s_setprio(0);
        }

        // ---- half B: same with s[4..7] and vrb
#pragma unroll
        for (int nf = 0; nf < 4; ++nf) {
            float p0 = __builtin_amdgcn_exp2f(s[4 + nf][0] - m);
            float p1 = __builtin_amdgcn_exp2f(s[4 + nf][1] - m);
            float p2 = __builtin_amdgcn_exp2f(s[4 + nf][2] - m);
            float p3 = __builtin_amdgcn_exp2f(s[4 + nf][3] - m);
            lsum += (p0 + p1) + (p2 + p3);
            uint2 pk;
            pk.x = cvt_pk_bf16(p0, p1);
            pk.y = cvt_pk_bf16(p2, p3);
            *reinterpret_cast<uint2*>(&P_s[w][c][16 * nf + 4 * g]) = pk;
        }
        {
            bf16x8 pa0 = *reinterpret_cast<const bf16x8*>(&P_s[w][c][8 * g]);
            bf16x8 pa1 = *reinterpret_cast<const bf16x8*>(&P_s[w][c][32 + 8 * g]);
            __builtin_amdgcn_s_setprio(1);
#pragma unroll
            for (int f = 0; f < 4; ++f) {
                o[f] = MFMA_16x16x32(pa0, vrb[2 * f],     o[f]);
                o[f] = MFMA_16x16x32(pa1, vrb[2 * f + 1], o[f]);
            }
            __builtin_amdgcn_s_setprio(0);
        }

        // ---- rotate K pair: readers done -> overwrite -> visible
        __syncthreads();
        if (pf) {
#pragma unroll
            for (int u = 0; u < 4; ++u)
                *reinterpret_cast<bf16x8*>(&K_s[srow + 32 * u][sch * 8]) = nk[u];
        }
        __syncthreads();
    }

    // ---- epilogue: reduce l over the 4 groups, normalize, store bf16
    lsum += __shfl_xor(lsum, 16);
    lsum += __shfl_xor(lsum, 32);
    const float linv = 1.0f / lsum;

    const size_t xbase = ((size_t)b * NCTX + q0) * EMB + h * DH;
#pragma unroll
    for (int r = 0; r < 4; ++r) {
        float lr = __shfl(linv, 4 * g + r);   // 1/l for q-local 4g+r
#pragma unroll
        for (int f = 0; f < 4; ++f) {
            float v = o[f][r] * lr;
            size_t addr = xbase + (size_t)(4 * g + r) * EMB + f * 16 + c;
            xb[addr] = f2bf(v);
        }
    }
}

// ---------- projection GEMM: Y[4096x768] = X @ W^T + bias (single-bf16) ----------
// 64-wide k rounds, clamped-index register prefetch (R9/R10, unchanged).
__global__ __launch_bounds__(256) void k_proj(
        const uint16_t* __restrict__ xb, const uint16_t* __restrict__ wb,
        const float* __restrict__ bias, float* __restrict__ out) {
    const int tid = threadIdx.x;
    const int w = tid >> 6;
    const int l = tid & 63;
    const int g = l >> 4;
    const int c = l & 15;
    const int m0 = blockIdx.x * 64 + w * 16;
    const int n0 = blockIdx.y * 64;

    __shared__ uint16_t W_s[64][72];

    f32x4 zero = {0.f, 0.f, 0.f, 0.f};
    f32x4 acc[4] = {zero, zero, zero, zero};

    const int srow = tid >> 2;   // 0..63
    const int sch  = tid & 3;    // 0..3
    constexpr int ROUNDS = EMB / 64;   // 12

    const uint16_t* whp = wb + (size_t)(n0 + srow) * EMB + sch * 8;
    const uint16_t* xhp = xb + (size_t)(m0 + c) * EMB + 8 * g;

    bf16x8 w0 = *reinterpret_cast<const bf16x8*>(whp);
    bf16x8 w1 = *reinterpret_cast<const bf16x8*>(whp + 32);
    bf16x8 a0 = *reinterpret_cast<const bf16x8*>(xhp);
    bf16x8 a1 = *reinterpret_cast<const bf16x8*>(xhp + 32);

    for (int rd = 0; rd < ROUNDS; ++rd) {
        __syncthreads();
        *reinterpret_cast<bf16x8*>(&W_s[srow][sch * 8])      = w0;
        *reinterpret_cast<bf16x8*>(&W_s[srow][32 + sch * 8]) = w1;
        __syncthreads();

        const int rn = (rd + 1 < ROUNDS) ? (rd + 1) : (ROUNDS - 1);
        bf16x8 w0n = *reinterpret_cast<const bf16x8*>(whp + (size_t)rn * 64);
        bf16x8 w1n = *reinterpret_cast<const bf16x8*>(whp + (size_t)rn * 64 + 32);
        bf16x8 a0n = *reinterpret_cast<const bf16x8*>(xhp + (size_t)rn * 64);
        bf16x8 a1n = *reinterpret_cast<const bf16x8*>(xhp + (size_t)rn * 64 + 32);

        __builtin_amdgcn_s_setprio(1);
#pragma unroll
        for (int nf = 0; nf < 4; ++nf) {
            bf16x8 b0 = *reinterpret_cast<const bf16x8*>(&W_s[nf * 16 + c][8 * g]);
            bf16x8 b1 = *reinterpret_cast<const bf16x8*>(&W_s[nf * 16 + c][32 + 8 * g]);
            acc[nf] = MFMA_16x16x32(a0, b0, acc[nf]);
            acc[nf] = MFMA_16x16x32(a1, b1, acc[nf]);
        }
        __builtin_amdgcn_s_setprio(0);

        w0 = w0n; w1 = w1n; a0 = a0n; a1 = a1n;
    }

#pragma unroll
    for (int nf = 0; nf < 4; ++nf) {
#pragma unroll
        for (int r = 0; r < 4; ++r) {
            int row = m0 + g * 4 + r;
            int col = n0 + nf * 16 + c;
            out[(size_t)row * EMB + col] = acc[nf][r] + bias[col];
        }
    }
}

extern "C" void kernel_launch(void* const* d_in, const int* in_sizes, int n_in,
                              void* d_out, int out_size, void* d_ws, size_t ws_size,
                              hipStream_t stream) {
    const float* q    = (const float*)d_in[0];
    const float* k    = (const float*)d_in[1];
    const float* v    = (const float*)d_in[2];
    const float* pw   = (const float*)d_in[3];
    const float* pb   = (const float*)d_in[4];
    float* out = (float*)d_out;

    const size_t nqkv = (size_t)BH * NCTX * DH;     // 3,145,728
    const size_t nx   = (size_t)BATCH * NCTX * EMB; // 3,145,728
    const size_t nw   = (size_t)EMB * EMB;          //   589,824

    uint8_t* ws = (uint8_t*)d_ws;
    uint16_t* kb = (uint16_t*)ws;              ws += nqkv * 2;
    uint16_t* vf = (uint16_t*)ws;              ws += nqkv * 2;
    uint16_t* xb = (uint16_t*)ws;              ws += nx * 2;
    uint16_t* wb = (uint16_t*)ws;              ws += nw * 2;

    // converts: K + W merged (Q handled inside k_attn)
    const int n4k = (int)(nqkv / 4);
    const int n4w = (int)(nw / 4);
    k_cvt2<<<(n4k + n4w + 255) / 256, 256, 0, stream>>>(k, kb, n4k, pw, wb, n4w);
    k_vt<<<dim3(NCTX / 64, BH), 256, 0, stream>>>(v, vf);

    // attention: R10 structure, KV-pair (128) loop
    k_attn<<<dim3(NCTX / 64, BH), 256, 0, stream>>>(q, kb, vf, xb);

    // projection
    k_proj<<<dim3((BATCH * NCTX) / 64, EMB / 64), 256, 0, stream>>>(xb, wb, pb, out);
}

// Round 13
// 74.699 us; speedup vs baseline: 1.1767x; 1.1767x over previous
//
#include <hip/hip_runtime.h>
#include <cstdint>

typedef short bf16x8 __attribute__((ext_vector_type(8)));
typedef float f32x4 __attribute__((ext_vector_type(4)));
typedef uint16_t u16x4 __attribute__((ext_vector_type(4)));

#define MFMA_16x16x32(a, b, c) __builtin_amdgcn_mfma_f32_16x16x32_bf16((a), (b), (c), 0, 0, 0)

static constexpr int BATCH = 2;
static constexpr int HEADS = 12;
static constexpr int BH    = BATCH * HEADS;   // 24
static constexpr int NCTX  = 2048;
static constexpr int DH    = 64;
static constexpr int EMB   = 768;

// 0.125 * log2(e): Q pre-scale so softmax runs in exp2 domain
static constexpr float QSCALE = 0.125f * 1.44269504088896340736f;

// ---------- bf16 helpers (raw-bit, RN rounding) ----------
__device__ __forceinline__ uint16_t f2bf(float x) {
    uint32_t u = __float_as_uint(x);
    u += 0x7FFFu + ((u >> 16) & 1u);
    return (uint16_t)(u >> 16);
}
__device__ __forceinline__ uint32_t cvt_pk_bf16(float lo, float hi) {
    uint32_t r;
    asm("v_cvt_pk_bf16_f32 %0, %1, %2" : "=v"(r) : "v"(lo), "v"(hi));
    return r;
}

// ---------- fused prep: V transpose->fragment layout + K/W convert ----------
// blocks [0, 768):            V transpose (bh = bid>>5, n0 = (bid&31)*64)
// blocks [768, 768+3648):     flat K (n4k) then W (n4w) float4->bf16 convert
// V fragment layout (R10): vf[((bh*32+t)*8 + slot)*512 + l*8 + j]
//   = V[kv=64t+32h+8g+j][d=16f+c], slot=2f+h, l=16g+c.
__global__ __launch_bounds__(256) void k_prep(
        const float* __restrict__ v, uint16_t* __restrict__ vt,
        const float* __restrict__ kf32, uint16_t* __restrict__ kb, int n4k,
        const float* __restrict__ w32, uint16_t* __restrict__ wb, int n4w) {
    const int bid = blockIdx.x;
    const int t   = threadIdx.x;

    if (bid < BH * (NCTX / 64)) {
        // ---- V transpose+convert tile
        __shared__ uint16_t tileT[64][72];   // [d][n_local]
        const int bh = bid >> 5;
        const int n0 = (bid & 31) * 64;

        const int r  = t >> 2;          // n-row within tile (0..63)
        const int cc = (t & 3) * 16;    // d-col base
        const float* vp = v + ((size_t)bh * NCTX + n0 + r) * DH + cc;
#pragma unroll
        for (int u = 0; u < 4; ++u) {
            float4 x = reinterpret_cast<const float4*>(vp)[u];
            tileT[cc + 4 * u + 0][r] = f2bf(x.x);
            tileT[cc + 4 * u + 1][r] = f2bf(x.y);
            tileT[cc + 4 * u + 2][r] = f2bf(x.z);
            tileT[cc + 4 * u + 3][r] = f2bf(x.w);
        }
        __syncthreads();

        const int l2 = t & 63;          // fragment lane
        const int s0 = t >> 6;          // 0..3
        const int gg = l2 >> 4;
        const int c2 = l2 & 15;
        uint16_t* vb = vt + ((size_t)bh * 32 + (n0 >> 6)) * 8 * 512;
#pragma unroll
        for (int u = 0; u < 2; ++u) {
            const int slot = s0 + 4 * u;        // 0..7
            const int f = slot >> 1, h = slot & 1;
            bf16x8 x = *reinterpret_cast<const bf16x8*>(&tileT[f * 16 + c2][h * 32 + 8 * gg]);
            *reinterpret_cast<bf16x8*>(vb + (size_t)slot * 512 + l2 * 8) = x;
        }
    } else {
        // ---- flat convert: K then W
        const int i = (bid - BH * (NCTX / 64)) * 256 + t;
        const float* src; uint16_t* dst; int j;
        if (i < n4k) { src = kf32; dst = kb; j = i; }
        else {
            j = i - n4k;
            if (j >= n4w) return;
            src = w32; dst = wb;
        }
        float4 x = reinterpret_cast<const float4*>(src)[j];
        u16x4 hv = {f2bf(x.x), f2bf(x.y), f2bf(x.z), f2bf(x.w)};
        reinterpret_cast<u16x4*>(dst)[j] = hv;
    }
}

// ---------- flash attention (R10, byte-identical) ----------
// grid: (NCTX/64, BH), block: 256 (4 waves). Wave owns 16 q-rows.
// V in registers via fragment-contiguous layout (8 coalesced 1KB loads per
// tile, issued at tile start). Double-buffered K LDS, one barrier pair per
// tile. Swapped QK^T, exp2 domain, shfl-free deferred max, vectorized P.
__global__ __launch_bounds__(256) void k_attn(
        const float* __restrict__ q, const uint16_t* __restrict__ kb,
        const uint16_t* __restrict__ vf, uint16_t* __restrict__ xb) {
    const int bh = blockIdx.y;
    const int b  = bh / HEADS;
    const int h  = bh % HEADS;
    const int tid = threadIdx.x;
    const int w = tid >> 6;
    const int l = tid & 63;
    const int g = l >> 4;    // 16-lane group 0..3
    const int c = l & 15;

    __shared__ uint16_t K_s[2][64][72];
    __shared__ uint16_t P_s[4][16][72];   // [wave][q][kv]

    const int q0 = blockIdx.x * 64 + w * 16;

    // Q fragments: load fp32 direct, scale by 0.125*log2e, convert in-reg
    bf16x8 qa[2];
    {
        const float* qp = q + ((size_t)bh * NCTX + q0 + c) * DH + 8 * g;
#pragma unroll
        for (int kf = 0; kf < 2; ++kf) {
            float4 x0 = *reinterpret_cast<const float4*>(qp + kf * 32);
            float4 x1 = *reinterpret_cast<const float4*>(qp + kf * 32 + 4);
            bf16x8 f;
            f[0] = (short)f2bf(x0.x * QSCALE); f[1] = (short)f2bf(x0.y * QSCALE);
            f[2] = (short)f2bf(x0.z * QSCALE); f[3] = (short)f2bf(x0.w * QSCALE);
            f[4] = (short)f2bf(x1.x * QSCALE); f[5] = (short)f2bf(x1.y * QSCALE);
            f[6] = (short)f2bf(x1.z * QSCALE); f[7] = (short)f2bf(x1.w * QSCALE);
            qa[kf] = f;
        }
    }

    f32x4 zero = {0.f, 0.f, 0.f, 0.f};
    f32x4 o[4] = {zero, zero, zero, zero};
    float m = -1e30f;     // running max (log2 units), per q=c (uniform across groups)
    float lsum = 0.f;     // lane-partial softmax denominator for q=c

    // K staging decomposition: 256 thr -> 32 rows x 8 chunks, two row-passes
    const int srow = tid >> 3;      // 0..31
    const int sch  = tid & 7;       // 0..7

    const uint16_t* kb_b = kb + (size_t)bh * NCTX * DH + srow * DH + sch * 8;
    // per-lane V fragment base: vf + bh*32*8*512 + l*8  (advance by (t*8+s)*512)
    const uint16_t* vf_b = vf + (size_t)bh * 32 * 8 * 512 + (size_t)l * 8;

    // prologue: stage K tile 0 into buffer 0
    {
        bf16x8 a0 = *reinterpret_cast<const bf16x8*>(kb_b);
        bf16x8 a1 = *reinterpret_cast<const bf16x8*>(kb_b + 32 * DH);
        *reinterpret_cast<bf16x8*>(&K_s[0][srow][sch * 8])      = a0;
        *reinterpret_cast<bf16x8*>(&K_s[0][srow + 32][sch * 8]) = a1;
    }
    __syncthreads();

    for (int t = 0; t < NCTX / 64; ++t) {
        const int cur = t & 1;
        const int nxt = cur ^ 1;

        // issue next-K-tile loads early (hide latency under compute)
        bf16x8 nk0, nk1;
        const bool pf = (t + 1) < NCTX / 64;
        if (pf) {
            const size_t ko = (size_t)(t + 1) * 64 * DH;
            nk0 = *reinterpret_cast<const bf16x8*>(kb_b + ko);
            nk1 = *reinterpret_cast<const bf16x8*>(kb_b + ko + 32 * DH);
        }

        // issue THIS tile's V fragment loads now (consumed at PV, ~full tile away)
        bf16x8 vr[8];
#pragma unroll
        for (int s = 0; s < 8; ++s)
            vr[s] = *reinterpret_cast<const bf16x8*>(vf_b + ((size_t)t * 8 + s) * 512);

        // ---- S^T = (K Q^T) single-bf16. s[nf][r] = S[kv=16nf+4g+r][q=c]
        f32x4 s[4] = {zero, zero, zero, zero};
        __builtin_amdgcn_s_setprio(1);
#pragma unroll
        for (int nf = 0; nf < 4; ++nf) {
#pragma unroll
            for (int kf = 0; kf < 2; ++kf) {
                bf16x8 bhf = *reinterpret_cast<const bf16x8*>(&K_s[cur][nf * 16 + c][kf * 32 + 8 * g]);
                s[nf] = MFMA_16x16x32(bhf, qa[kf], s[nf]);
            }
        }
        __builtin_amdgcn_s_setprio(0);

        // ---- per-lane partial max over this lane's 16 kv slots (tree, depth 4)
        float pm0 = fmaxf(fmaxf(s[0][0], s[0][1]), fmaxf(s[0][2], s[0][3]));
        float pm1 = fmaxf(fmaxf(s[1][0], s[1][1]), fmaxf(s[1][2], s[1][3]));
        float pm2 = fmaxf(fmaxf(s[2][0], s[2][1]), fmaxf(s[2][2], s[2][3]));
        float pm3 = fmaxf(fmaxf(s[3][0], s[3][1]), fmaxf(s[3][2], s[3][3]));
        float pmax = fmaxf(fmaxf(pm0, pm1), fmaxf(pm2, pm3));

        // deferred max, shfl-free common path (equivalence: see R9)
        if (!__all(pmax <= m + 11.0f)) {
            float smax = fmaxf(pmax, __shfl_xor(pmax, 16));
            smax = fmaxf(smax, __shfl_xor(smax, 32));
            float mnew = fmaxf(m, smax);
            float corr = __builtin_amdgcn_exp2f(m - mnew);
            m = mnew;
            lsum *= corr;
#pragma unroll
            for (int r = 0; r < 4; ++r) {
                float cr = __shfl(corr, 4 * g + r);   // corr for q-local 4g+r
#pragma unroll
                for (int f = 0; f < 4; ++f) o[f][r] *= cr;
            }
        }

        // p = exp2(s - m); pack pairs and write 4 contiguous kv per lane (b64)
#pragma unroll
        for (int nf = 0; nf < 4; ++nf) {
            float p0 = __builtin_amdgcn_exp2f(s[nf][0] - m);
            float p1 = __builtin_amdgcn_exp2f(s[nf][1] - m);
            float p2 = __builtin_amdgcn_exp2f(s[nf][2] - m);
            float p3 = __builtin_amdgcn_exp2f(s[nf][3] - m);
            lsum += (p0 + p1) + (p2 + p3);
            uint2 pk;
            pk.x = cvt_pk_bf16(p0, p1);
            pk.y = cvt_pk_bf16(p2, p3);
            *reinterpret_cast<uint2*>(&P_s[w][c][16 * nf + 4 * g]) = pk;
        }

        // ---- O += P V (V fragments already in registers)
        bf16x8 pa0 = *reinterpret_cast<const bf16x8*>(&P_s[w][c][8 * g]);
        bf16x8 pa1 = *reinterpret_cast<const bf16x8*>(&P_s[w][c][32 + 8 * g]);
        __builtin_amdgcn_s_setprio(1);
#pragma unroll
        for (int f = 0; f < 4; ++f) {
            o[f] = MFMA_16x16x32(pa0, vr[2 * f],     o[f]);
            o[f] = MFMA_16x16x32(pa1, vr[2 * f + 1], o[f]);
        }
        __builtin_amdgcn_s_setprio(0);

        // ---- write prefetched K tile to the ALTERNATE buffer, then one barrier
        if (pf) {
            *reinterpret_cast<bf16x8*>(&K_s[nxt][srow][sch * 8])      = nk0;
            *reinterpret_cast<bf16x8*>(&K_s[nxt][srow + 32][sch * 8]) = nk1;
        }
        __syncthreads();
    }

    // ---- epilogue: reduce l over the 4 groups, normalize, store bf16
    lsum += __shfl_xor(lsum, 16);
    lsum += __shfl_xor(lsum, 32);
    const float linv = 1.0f / lsum;

    const size_t xbase = ((size_t)b * NCTX + q0) * EMB + h * DH;
#pragma unroll
    for (int r = 0; r < 4; ++r) {
        float lr = __shfl(linv, 4 * g + r);   // 1/l for q-local 4g+r
#pragma unroll
        for (int f = 0; f < 4; ++f) {
            float v = o[f][r] * lr;
            size_t addr = xbase + (size_t)(4 * g + r) * EMB + f * 16 + c;
            xb[addr] = f2bf(v);
        }
    }
}

// ---------- projection GEMM: Y[4096x768] = X @ W^T + bias (single-bf16) ----------
// 64-wide k rounds, clamped-index register prefetch (R9/R10, unchanged).
__global__ __launch_bounds__(256) void k_proj(
        const uint16_t* __restrict__ xb, const uint16_t* __restrict__ wb,
        const float* __restrict__ bias, float* __restrict__ out) {
    const int tid = threadIdx.x;
    const int w = tid >> 6;
    const int l = tid & 63;
    const int g = l >> 4;
    const int c = l & 15;
    const int m0 = blockIdx.x * 64 + w * 16;
    const int n0 = blockIdx.y * 64;

    __shared__ uint16_t W_s[64][72];

    f32x4 zero = {0.f, 0.f, 0.f, 0.f};
    f32x4 acc[4] = {zero, zero, zero, zero};

    const int srow = tid >> 2;   // 0..63
    const int sch  = tid & 3;    // 0..3
    constexpr int ROUNDS = EMB / 64;   // 12

    const uint16_t* whp = wb + (size_t)(n0 + srow) * EMB + sch * 8;
    const uint16_t* xhp = xb + (size_t)(m0 + c) * EMB + 8 * g;

    bf16x8 w0 = *reinterpret_cast<const bf16x8*>(whp);
    bf16x8 w1 = *reinterpret_cast<const bf16x8*>(whp + 32);
    bf16x8 a0 = *reinterpret_cast<const bf16x8*>(xhp);
    bf16x8 a1 = *reinterpret_cast<const bf16x8*>(xhp + 32);

    for (int rd = 0; rd < ROUNDS; ++rd) {
        __syncthreads();
        *reinterpret_cast<bf16x8*>(&W_s[srow][sch * 8])      = w0;
        *reinterpret_cast<bf16x8*>(&W_s[srow][32 + sch * 8]) = w1;
        __syncthreads();

        const int rn = (rd + 1 < ROUNDS) ? (rd + 1) : (ROUNDS - 1);
        bf16x8 w0n = *reinterpret_cast<const bf16x8*>(whp + (size_t)rn * 64);
        bf16x8 w1n = *reinterpret_cast<const bf16x8*>(whp + (size_t)rn * 64 + 32);
        bf16x8 a0n = *reinterpret_cast<const bf16x8*>(xhp + (size_t)rn * 64);
        bf16x8 a1n = *reinterpret_cast<const bf16x8*>(xhp + (size_t)rn * 64 + 32);

        __builtin_amdgcn_s_setprio(1);
#pragma unroll
        for (int nf = 0; nf < 4; ++nf) {
            bf16x8 b0 = *reinterpret_cast<const bf16x8*>(&W_s[nf * 16 + c][8 * g]);
            bf16x8 b1 = *reinterpret_cast<const bf16x8*>(&W_s[nf * 16 + c][32 + 8 * g]);
            acc[nf] = MFMA_16x16x32(a0, b0, acc[nf]);
            acc[nf] = MFMA_16x16x32(a1, b1, acc[nf]);
        }
        __builtin_amdgcn_s_setprio(0);

        w0 = w0n; w1 = w1n; a0 = a0n; a1 = a1n;
    }

#pragma unroll
    for (int nf = 0; nf < 4; ++nf) {
#pragma unroll
        for (int r = 0; r < 4; ++r) {
            int row = m0 + g * 4 + r;
            int col = n0 + nf * 16 + c;
            out[(size_t)row * EMB + col] = acc[nf][r] + bias[col];
        }
    }
}

extern "C" void kernel_launch(void* const* d_in, const int* in_sizes, int n_in,
                              void* d_out, int out_size, void* d_ws, size_t ws_size,
                              hipStream_t stream) {
    const float* q    = (const float*)d_in[0];
    const float* k    = (const float*)d_in[1];
    const float* v    = (const float*)d_in[2];
    const float* pw   = (const float*)d_in[3];
    const float* pb   = (const float*)d_in[4];
    float* out = (float*)d_out;

    const size_t nqkv = (size_t)BH * NCTX * DH;     // 3,145,728
    const size_t nx   = (size_t)BATCH * NCTX * EMB; // 3,145,728
    const size_t nw   = (size_t)EMB * EMB;          //   589,824

    uint8_t* ws = (uint8_t*)d_ws;
    uint16_t* kb = (uint16_t*)ws;              ws += nqkv * 2;
    uint16_t* vf = (uint16_t*)ws;              ws += nqkv * 2;
    uint16_t* xb = (uint16_t*)ws;              ws += nx * 2;
    uint16_t* wb = (uint16_t*)ws;              ws += nw * 2;

    // fused prep: V transpose (768 blocks) + K/W convert (3648 blocks)
    const int n4k = (int)(nqkv / 4);
    const int n4w = (int)(nw / 4);
    const int nprep = BH * (NCTX / 64) + (n4k + n4w + 255) / 256;
    k_prep<<<nprep, 256, 0, stream>>>(v, vf, k, kb, n4k, pw, wb, n4w);

    // attention (R10 structure)
    k_attn<<<dim3(NCTX / 64, BH), 256, 0, stream>>>(q, kb, vf, xb);

    // projection
    k_proj<<<dim3((BATCH * NCTX) / 64, EMB / 64), 256, 0, stream>>>(xb, wb, pb, out);
}